// Round 1
// baseline (4074.384 us; speedup 1.0000x reference)
//
#include <hip/hip_runtime.h>

// Problem constants (from reference)
#define N_NODES 20000
#define F_IN    512
#define D_H     256
#define E_EDGES 200000
#define L_LAYERS 3
#define T_ETYPES 2

#define BM 64
#define BN 64
#define BK 16

// C[M, 256] = act( A0 @ W0^T (+ A1 @ W1^T) + bias ), W row-major (256, K)
template <int NA>
__global__ __launch_bounds__(256) void gemm_bias_act(
    const float* __restrict__ A0, const float* __restrict__ A1,
    const float* __restrict__ W0, const float* __restrict__ W1,
    const float* __restrict__ bias, float* __restrict__ C,
    int M, int K, int relu)
{
    __shared__ float sA[BK][BM + 4];
    __shared__ float sW[BK][BN + 4];
    const int bm = blockIdx.y * BM;
    const int bn = blockIdx.x * BN;
    const int tid = threadIdx.x;
    const int tx = tid & 15;
    const int ty = tid >> 4;
    const int lrow = tid >> 2;        // 0..63
    const int lk   = (tid & 3) << 2;  // 0,4,8,12

    float acc[4][4] = {};

    for (int pass = 0; pass < NA; ++pass) {
        const float* __restrict__ A = (pass == 0) ? A0 : A1;
        const float* __restrict__ W = (pass == 0) ? W0 : W1;
        for (int k0 = 0; k0 < K; k0 += BK) {
            float4 va = make_float4(0.f, 0.f, 0.f, 0.f);
            const int gr = bm + lrow;
            if (gr < M) va = *(const float4*)(A + (size_t)gr * K + k0 + lk);
            const float4 vw = *(const float4*)(W + (size_t)(bn + lrow) * K + k0 + lk);
            __syncthreads();
            sA[lk + 0][lrow] = va.x; sA[lk + 1][lrow] = va.y;
            sA[lk + 2][lrow] = va.z; sA[lk + 3][lrow] = va.w;
            sW[lk + 0][lrow] = vw.x; sW[lk + 1][lrow] = vw.y;
            sW[lk + 2][lrow] = vw.z; sW[lk + 3][lrow] = vw.w;
            __syncthreads();
#pragma unroll
            for (int k = 0; k < BK; ++k) {
                const float4 a4 = *(const float4*)(&sA[k][ty << 2]);
                const float4 b4 = *(const float4*)(&sW[k][tx << 2]);
                const float av[4] = {a4.x, a4.y, a4.z, a4.w};
                const float bv[4] = {b4.x, b4.y, b4.z, b4.w};
#pragma unroll
                for (int i = 0; i < 4; ++i)
#pragma unroll
                    for (int j = 0; j < 4; ++j)
                        acc[i][j] = fmaf(av[i], bv[j], acc[i][j]);
            }
        }
    }

#pragma unroll
    for (int i = 0; i < 4; ++i) {
        const int r = bm + (ty << 2) + i;
        if (r >= M) continue;
        float* crow = C + (size_t)r * D_H + bn + (tx << 2);
        float4 o;
        float* op = &o.x;
#pragma unroll
        for (int j = 0; j < 4; ++j) {
            float v = acc[i][j] + bias[bn + (tx << 2) + j];
            if (relu) v = fmaxf(v, 0.f);
            op[j] = v;
        }
        *(float4*)crow = o;
    }
}

// neigh[dst[e]] = max(neigh[dst[e]], hp[src[e]]) ; hp >= 0 so int-compare == float-compare
__global__ __launch_bounds__(256) void scatter_max_kernel(
    const float* __restrict__ hp, const int* __restrict__ src,
    const int* __restrict__ dst, int* __restrict__ neigh, int E)
{
    const int e = blockIdx.x * 4 + (threadIdx.x >> 6);
    if (e >= E) return;
    const int lane = threadIdx.x & 63;
    const int s = src[e];
    const int d = dst[e];
    const float4 v = *(const float4*)(hp + (size_t)s * D_H + lane * 4);
    int* base = neigh + (size_t)d * D_H + lane * 4;
    atomicMax(base + 0, __float_as_int(v.x));
    atomicMax(base + 1, __float_as_int(v.y));
    atomicMax(base + 2, __float_as_int(v.z));
    atomicMax(base + 3, __float_as_int(v.w));
}

// out[row] (+)= LayerNorm( maybe_relu(rst[row]) ) * gamma + beta ; one wave per row
__global__ __launch_bounds__(256) void ln_acc_kernel(
    const float* __restrict__ rst, const float* __restrict__ gamma,
    const float* __restrict__ beta, float* __restrict__ out,
    int n, int relu, int accumulate)
{
    const int row = blockIdx.x * 4 + (threadIdx.x >> 6);
    if (row >= n) return;
    const int lane = threadIdx.x & 63;
    float4 v = *(const float4*)(rst + (size_t)row * D_H + lane * 4);
    if (relu) {
        v.x = fmaxf(v.x, 0.f); v.y = fmaxf(v.y, 0.f);
        v.z = fmaxf(v.z, 0.f); v.w = fmaxf(v.w, 0.f);
    }
    float s = v.x + v.y + v.z + v.w;
#pragma unroll
    for (int off = 32; off > 0; off >>= 1) s += __shfl_xor(s, off);
    const float mean = s * (1.f / 256.f);
    const float d0 = v.x - mean, d1 = v.y - mean, d2 = v.z - mean, d3 = v.w - mean;
    float q = d0 * d0 + d1 * d1 + d2 * d2 + d3 * d3;
#pragma unroll
    for (int off = 32; off > 0; off >>= 1) q += __shfl_xor(q, off);
    const float inv = rsqrtf(q * (1.f / 256.f) + 1e-5f);
    const float4 g = *(const float4*)(gamma + lane * 4);
    const float4 b = *(const float4*)(beta + lane * 4);
    float4 o;
    o.x = d0 * inv * g.x + b.x;
    o.y = d1 * inv * g.y + b.y;
    o.z = d2 * inv * g.z + b.z;
    o.w = d3 * inv * g.w + b.w;
    float* orow = out + (size_t)row * D_H + lane * 4;
    if (accumulate) {
        const float4 p = *(const float4*)orow;
        o.x += p.x; o.y += p.y; o.z += p.z; o.w += p.w;
    }
    *(float4*)orow = o;
}

extern "C" void kernel_launch(void* const* d_in, const int* in_sizes, int n_in,
                              void* d_out, int out_size, void* d_ws, size_t ws_size,
                              hipStream_t stream)
{
    const float* x      = (const float*)d_in[0];
    const int*   src    = (const int*)d_in[1];
    const int*   dst    = (const int*)d_in[2];
    const float* Wlin   = (const float*)d_in[3];
    const float* blin   = (const float*)d_in[4];
    const float* Wpool  = (const float*)d_in[5];
    const float* bpool  = (const float*)d_in[6];
    const float* Wself  = (const float*)d_in[7];
    const float* Wneigh = (const float*)d_in[8];
    const float* bconv  = (const float*)d_in[9];
    const float* gamma  = (const float*)d_in[10];
    const float* beta   = (const float*)d_in[11];

    const size_t NB = (size_t)N_NODES * D_H;
    float* bufA = (float*)d_ws;      // h
    float* bufB = bufA + NB;         // hp / rst
    float* bufC = bufB + NB;         // neigh
    float* bufD = bufC + NB;         // out accumulator

    const dim3 gblk(256);
    const dim3 ggrid(D_H / BN, (N_NODES + BM - 1) / BM);
    const dim3 sgrid((E_EDGES + 3) / 4);
    const dim3 lgrid((N_NODES + 3) / 4);

    // h = x @ Wlin^T + blin
    gemm_bias_act<1><<<ggrid, gblk, 0, stream>>>(x, nullptr, Wlin, nullptr, blin,
                                                 bufA, N_NODES, F_IN, 0);

    float* h = bufA;
    float* out = bufD;
    for (int l = 0; l < L_LAYERS; ++l) {
        float* outbuf = (l == L_LAYERS - 1) ? (float*)d_out : out;
        for (int t = 0; t < T_ETYPES; ++t) {
            const size_t wo = ((size_t)l * T_ETYPES + t) * D_H * D_H;
            const size_t bo = ((size_t)l * T_ETYPES + t) * D_H;
            // hp = relu(h @ Wpool^T + bpool)
            gemm_bias_act<1><<<ggrid, gblk, 0, stream>>>(h, nullptr, Wpool + wo, nullptr,
                                                         bpool + bo, bufB, N_NODES, D_H, 1);
            // neigh = segment_max(hp[src], dst) with 0 init (hp >= 0)
            hipMemsetAsync(bufC, 0, NB * sizeof(float), stream);
            scatter_max_kernel<<<sgrid, gblk, 0, stream>>>(
                bufB, src + (size_t)t * E_EDGES, dst + (size_t)t * E_EDGES,
                (int*)bufC, E_EDGES);
            // rst = h @ Wself^T + neigh @ Wneigh^T + bconv
            gemm_bias_act<2><<<ggrid, gblk, 0, stream>>>(h, bufC, Wself + wo, Wneigh + wo,
                                                         bconv + bo, bufB, N_NODES, D_H, 0);
            // out (+)= LN(maybe_relu(rst))
            ln_acc_kernel<<<lgrid, gblk, 0, stream>>>(bufB, gamma + bo, beta + bo, outbuf,
                                                      N_NODES, (l < L_LAYERS - 1) ? 1 : 0, t);
        }
        if (l < L_LAYERS - 1) { float* tmp = h; h = out; out = tmp; }
    }
}

// Round 2
// 1280.271 us; speedup vs baseline: 3.1824x; 3.1824x over previous
//
#include <hip/hip_runtime.h>

// Problem constants (from reference)
#define N_NODES 20000
#define F_IN    512
#define D_H     256
#define E_EDGES 200000
#define L_LAYERS 3
#define T_ETYPES 2

#define BM 64
#define BN 64
#define BK 16

// C[M, 256] = act( A0 @ W0^T (+ A1 @ W1^T) + bias ), W row-major (256, K)
template <int NA>
__global__ __launch_bounds__(256) void gemm_bias_act(
    const float* __restrict__ A0, const float* __restrict__ A1,
    const float* __restrict__ W0, const float* __restrict__ W1,
    const float* __restrict__ bias, float* __restrict__ C,
    int M, int K, int relu)
{
    __shared__ float sA[BK][BM + 4];
    __shared__ float sW[BK][BN + 4];
    const int bm = blockIdx.y * BM;
    const int bn = blockIdx.x * BN;
    const int tid = threadIdx.x;
    const int tx = tid & 15;
    const int ty = tid >> 4;
    const int lrow = tid >> 2;        // 0..63
    const int lk   = (tid & 3) << 2;  // 0,4,8,12

    float acc[4][4] = {};

    for (int pass = 0; pass < NA; ++pass) {
        const float* __restrict__ A = (pass == 0) ? A0 : A1;
        const float* __restrict__ W = (pass == 0) ? W0 : W1;
        for (int k0 = 0; k0 < K; k0 += BK) {
            float4 va = make_float4(0.f, 0.f, 0.f, 0.f);
            const int gr = bm + lrow;
            if (gr < M) va = *(const float4*)(A + (size_t)gr * K + k0 + lk);
            const float4 vw = *(const float4*)(W + (size_t)(bn + lrow) * K + k0 + lk);
            __syncthreads();
            sA[lk + 0][lrow] = va.x; sA[lk + 1][lrow] = va.y;
            sA[lk + 2][lrow] = va.z; sA[lk + 3][lrow] = va.w;
            sW[lk + 0][lrow] = vw.x; sW[lk + 1][lrow] = vw.y;
            sW[lk + 2][lrow] = vw.z; sW[lk + 3][lrow] = vw.w;
            __syncthreads();
#pragma unroll
            for (int k = 0; k < BK; ++k) {
                const float4 a4 = *(const float4*)(&sA[k][ty << 2]);
                const float4 b4 = *(const float4*)(&sW[k][tx << 2]);
                const float av[4] = {a4.x, a4.y, a4.z, a4.w};
                const float bv[4] = {b4.x, b4.y, b4.z, b4.w};
#pragma unroll
                for (int i = 0; i < 4; ++i)
#pragma unroll
                    for (int j = 0; j < 4; ++j)
                        acc[i][j] = fmaf(av[i], bv[j], acc[i][j]);
            }
        }
    }

#pragma unroll
    for (int i = 0; i < 4; ++i) {
        const int r = bm + (ty << 2) + i;
        if (r >= M) continue;
        float* crow = C + (size_t)r * D_H + bn + (tx << 2);
        float4 o;
        float* op = &o.x;
#pragma unroll
        for (int j = 0; j < 4; ++j) {
            float v = acc[i][j] + bias[bn + (tx << 2) + j];
            if (relu) v = fmaxf(v, 0.f);
            op[j] = v;
        }
        *(float4*)crow = o;
    }
}

// ---------------- CSR build (per etype, once per launch) ----------------

__global__ __launch_bounds__(256) void zero_int_kernel(int* p, int n)
{
    int i = blockIdx.x * 256 + threadIdx.x;
    if (i < n) p[i] = 0;
}

__global__ __launch_bounds__(256) void count_deg_kernel(
    const int* __restrict__ dst, int* __restrict__ cnt, int E)
{
    int e = blockIdx.x * 256 + threadIdx.x;
    if (e < E) atomicAdd(&cnt[dst[e]], 1);
}

// single-block exclusive scan: off[0]=0, off[i+1]=sum(cnt[0..i]); also cursor[i]=off[i]
__global__ __launch_bounds__(1024) void scan_kernel(
    const int* __restrict__ cnt, int* __restrict__ off, int* __restrict__ cursor, int n)
{
    __shared__ int tmp[1024];
    __shared__ int carry;
    if (threadIdx.x == 0) carry = 0;
    __syncthreads();
    for (int base = 0; base < n; base += 1024) {
        const int i = base + threadIdx.x;
        const int v = (i < n) ? cnt[i] : 0;
        tmp[threadIdx.x] = v;
        __syncthreads();
#pragma unroll
        for (int o = 1; o < 1024; o <<= 1) {
            const int t = (threadIdx.x >= o) ? tmp[threadIdx.x - o] : 0;
            __syncthreads();
            tmp[threadIdx.x] += t;
            __syncthreads();
        }
        const int total = tmp[1023];
        if (i < n) {
            const int incl = tmp[threadIdx.x];
            off[i + 1] = carry + incl;
            cursor[i] = carry + incl - v;  // exclusive
        }
        __syncthreads();
        if (threadIdx.x == 0) carry += total;
        __syncthreads();
    }
    if (threadIdx.x == 0) off[0] = 0;
}

__global__ __launch_bounds__(256) void fill_csr_kernel(
    const int* __restrict__ src, const int* __restrict__ dst,
    int* __restrict__ cursor, int* __restrict__ esrc, int E)
{
    int e = blockIdx.x * 256 + threadIdx.x;
    if (e < E) {
        const int pos = atomicAdd(&cursor[dst[e]], 1);
        esrc[pos] = src[e];
    }
}

// ---------------- segment max via gather: one wave per dst node ----------------
__global__ __launch_bounds__(256) void seg_max_kernel(
    const float* __restrict__ hp, const int* __restrict__ off,
    const int* __restrict__ esrc, float* __restrict__ neigh, int n)
{
    const int node = blockIdx.x * 4 + (threadIdx.x >> 6);
    if (node >= n) return;
    const int lane = threadIdx.x & 63;
    const int e0 = off[node], e1 = off[node + 1];
    float4 acc = make_float4(0.f, 0.f, 0.f, 0.f);
    for (int e = e0; e < e1; ++e) {
        const int s = esrc[e];
        const float4 v = *(const float4*)(hp + (size_t)s * D_H + lane * 4);
        acc.x = fmaxf(acc.x, v.x);
        acc.y = fmaxf(acc.y, v.y);
        acc.z = fmaxf(acc.z, v.z);
        acc.w = fmaxf(acc.w, v.w);
    }
    *(float4*)(neigh + (size_t)node * D_H + lane * 4) = acc;
}

// out[row] (+)= LayerNorm( maybe_relu(rst[row]) ) * gamma + beta ; one wave per row
__global__ __launch_bounds__(256) void ln_acc_kernel(
    const float* __restrict__ rst, const float* __restrict__ gamma,
    const float* __restrict__ beta, float* __restrict__ out,
    int n, int relu, int accumulate)
{
    const int row = blockIdx.x * 4 + (threadIdx.x >> 6);
    if (row >= n) return;
    const int lane = threadIdx.x & 63;
    float4 v = *(const float4*)(rst + (size_t)row * D_H + lane * 4);
    if (relu) {
        v.x = fmaxf(v.x, 0.f); v.y = fmaxf(v.y, 0.f);
        v.z = fmaxf(v.z, 0.f); v.w = fmaxf(v.w, 0.f);
    }
    float s = v.x + v.y + v.z + v.w;
#pragma unroll
    for (int off = 32; off > 0; off >>= 1) s += __shfl_xor(s, off);
    const float mean = s * (1.f / 256.f);
    const float d0 = v.x - mean, d1 = v.y - mean, d2 = v.z - mean, d3 = v.w - mean;
    float q = d0 * d0 + d1 * d1 + d2 * d2 + d3 * d3;
#pragma unroll
    for (int off = 32; off > 0; off >>= 1) q += __shfl_xor(q, off);
    const float inv = rsqrtf(q * (1.f / 256.f) + 1e-5f);
    const float4 g = *(const float4*)(gamma + lane * 4);
    const float4 b = *(const float4*)(beta + lane * 4);
    float4 o;
    o.x = d0 * inv * g.x + b.x;
    o.y = d1 * inv * g.y + b.y;
    o.z = d2 * inv * g.z + b.z;
    o.w = d3 * inv * g.w + b.w;
    float* orow = out + (size_t)row * D_H + lane * 4;
    if (accumulate) {
        const float4 p = *(const float4*)orow;
        o.x += p.x; o.y += p.y; o.z += p.z; o.w += p.w;
    }
    *(float4*)orow = o;
}

extern "C" void kernel_launch(void* const* d_in, const int* in_sizes, int n_in,
                              void* d_out, int out_size, void* d_ws, size_t ws_size,
                              hipStream_t stream)
{
    const float* x      = (const float*)d_in[0];
    const int*   src    = (const int*)d_in[1];
    const int*   dst    = (const int*)d_in[2];
    const float* Wlin   = (const float*)d_in[3];
    const float* blin   = (const float*)d_in[4];
    const float* Wpool  = (const float*)d_in[5];
    const float* bpool  = (const float*)d_in[6];
    const float* Wself  = (const float*)d_in[7];
    const float* Wneigh = (const float*)d_in[8];
    const float* bconv  = (const float*)d_in[9];
    const float* gamma  = (const float*)d_in[10];
    const float* beta   = (const float*)d_in[11];

    const size_t NB = (size_t)N_NODES * D_H;
    float* bufA = (float*)d_ws;      // h (layer input)
    float* bufB = bufA + NB;         // hp / rst
    float* bufC = bufB + NB;         // neigh
    int*   ibase = (int*)(bufC + NB);
    int* off[T_ETYPES];   // 20001 each
    int* cur[T_ETYPES];   // 20000 each
    int* esrc[T_ETYPES];  // 200000 each
    {
        int* p = ibase;
        for (int t = 0; t < T_ETYPES; ++t) { off[t] = p; p += (N_NODES + 1); }
        for (int t = 0; t < T_ETYPES; ++t) { cur[t] = p; p += N_NODES; }
        for (int t = 0; t < T_ETYPES; ++t) { esrc[t] = p; p += E_EDGES; }
    }

    const dim3 blk(256);
    const dim3 ggrid(D_H / BN, (N_NODES + BM - 1) / BM);
    const dim3 egrid((E_EDGES + 255) / 256);
    const dim3 ngrid((N_NODES + 255) / 256);
    const dim3 wgrid((N_NODES + 3) / 4);

    // ---- build CSR for both etypes (reused across all layers) ----
    for (int t = 0; t < T_ETYPES; ++t) {
        const int* dst_t = dst + (size_t)t * E_EDGES;
        const int* src_t = src + (size_t)t * E_EDGES;
        zero_int_kernel<<<ngrid, blk, 0, stream>>>(cur[t], N_NODES);  // reuse cur as cnt
        count_deg_kernel<<<egrid, blk, 0, stream>>>(dst_t, cur[t], E_EDGES);
        scan_kernel<<<1, 1024, 0, stream>>>(cur[t], off[t], cur[t], N_NODES);
        fill_csr_kernel<<<egrid, blk, 0, stream>>>(src_t, dst_t, cur[t], esrc[t], E_EDGES);
    }

    // h = x @ Wlin^T + blin
    gemm_bias_act<1><<<ggrid, blk, 0, stream>>>(x, nullptr, Wlin, nullptr, blin,
                                                bufA, N_NODES, F_IN, 0);

    // h ping-pongs bufA <-> d_out; final layer lands in d_out.
    float* h = bufA;
    float* out = (float*)d_out;
    for (int l = 0; l < L_LAYERS; ++l) {
        for (int t = 0; t < T_ETYPES; ++t) {
            const size_t wo = ((size_t)l * T_ETYPES + t) * D_H * D_H;
            const size_t bo = ((size_t)l * T_ETYPES + t) * D_H;
            // hp = relu(h @ Wpool^T + bpool)
            gemm_bias_act<1><<<ggrid, blk, 0, stream>>>(h, nullptr, Wpool + wo, nullptr,
                                                        bpool + bo, bufB, N_NODES, D_H, 1);
            // neigh = segment_max over incoming edges (0 for zero-degree; hp >= 0)
            seg_max_kernel<<<wgrid, blk, 0, stream>>>(bufB, off[t], esrc[t], bufC, N_NODES);
            // rst = h @ Wself^T + neigh @ Wneigh^T + bconv
            gemm_bias_act<2><<<ggrid, blk, 0, stream>>>(h, bufC, Wself + wo, Wneigh + wo,
                                                        bconv + bo, bufB, N_NODES, D_H, 0);
            // out (+)= LN(maybe_relu(rst))
            ln_acc_kernel<<<wgrid, blk, 0, stream>>>(bufB, gamma + bo, beta + bo, out,
                                                     N_NODES, (l < L_LAYERS - 1) ? 1 : 0, t);
        }
        float* tmp = h; h = out; out = tmp;  // after last layer: h == d_out (result)
    }
}

// Round 3
// 618.872 us; speedup vs baseline: 6.5836x; 2.0687x over previous
//
#include <hip/hip_runtime.h>

// Problem constants (from reference)
#define N_NODES 20000
#define F_IN    512
#define D_H     256
#define E_EDGES 200000
#define L_LAYERS 3
#define T_ETYPES 2

typedef __attribute__((ext_vector_type(8))) short bf16x8;
typedef __attribute__((ext_vector_type(4))) float f32x4;

__device__ __forceinline__ unsigned short f2b(float f) {
    unsigned int u = __float_as_uint(f);
    u = (u + 0x7FFFu + ((u >> 16) & 1u)) >> 16;   // round-nearest-even
    return (unsigned short)u;
}

// ---------------- bf16 MFMA GEMM ----------------
// C[M,256] = act( A0@W0^T (+ A1@W1^T) + bias ); A,W bf16 (W row-major [256,K]).
// Block tile 64x128, 4 waves (2x2), wave tile 32x64 = 2x4 of 16x16 MFMA tiles.
// LDS in MFMA fragment order: per 16x32 tile, element (mloc,kg,j) at lane*8+j
// where lane = kg*16+mloc  ->  ds_read_b128 at base+lane*16 (conflict-free).
template <int NA, int OUT_BF16, int RELU>
__global__ __launch_bounds__(256) void gemm_mfma(
    const unsigned short* __restrict__ A0, const unsigned short* __restrict__ A1,
    const unsigned short* __restrict__ W0, const unsigned short* __restrict__ W1,
    const float* __restrict__ bias, void* __restrict__ Cout, int M, int K)
{
    __shared__ unsigned short sA[64 * 32];    // 4 tiles * 512
    __shared__ unsigned short sB[128 * 32];   // 8 tiles * 512
    const int tid  = threadIdx.x;
    const int lane = tid & 63;
    const int w    = tid >> 6;
    const int wm   = w >> 1, wn = w & 1;
    const int bm   = blockIdx.y * 64;
    const int bn   = blockIdx.x * 128;

    // A staging: thread -> (row sma 0..63, k-quarter qa 0..3), one uint4 (8 bf16)
    const int sma = tid >> 2, qa = tid & 3;
    const int aoff = ((sma >> 4) << 9) + ((qa * 16 + (sma & 15)) << 3);
    const bool aval = (bm + sma) < M;
    // B staging: thread -> (row snb 0..127, half hb 0..1), two uint4
    const int snb = tid >> 1, hb = tid & 1;
    const int boff0 = ((snb >> 4) << 9) + (((hb * 2 + 0) * 16 + (snb & 15)) << 3);
    const int boff1 = ((snb >> 4) << 9) + (((hb * 2 + 1) * 16 + (snb & 15)) << 3);

    f32x4 acc[2][4] = {};

    for (int pass = 0; pass < NA; ++pass) {
        const unsigned short* __restrict__ A = pass ? A1 : A0;
        const unsigned short* __restrict__ W = pass ? W1 : W0;
        const unsigned short* aPtr = A + (size_t)min(bm + sma, M - 1) * K + qa * 8;
        const unsigned short* bPtr = W + (size_t)(bn + snb) * K + hb * 16;
        for (int k0 = 0; k0 < K; k0 += 32) {
            uint4 av = make_uint4(0u, 0u, 0u, 0u);
            if (aval) av = *(const uint4*)(aPtr + k0);
            const uint4 bv0 = *(const uint4*)(bPtr + k0);
            const uint4 bv1 = *(const uint4*)(bPtr + k0 + 8);
            __syncthreads();
            *(uint4*)(sA + aoff)  = av;
            *(uint4*)(sB + boff0) = bv0;
            *(uint4*)(sB + boff1) = bv1;
            __syncthreads();
            bf16x8 af[2], bf[4];
#pragma unroll
            for (int i = 0; i < 2; ++i)
                af[i] = *(const bf16x8*)(sA + ((wm * 2 + i) << 9) + lane * 8);
#pragma unroll
            for (int j = 0; j < 4; ++j)
                bf[j] = *(const bf16x8*)(sB + ((wn * 4 + j) << 9) + lane * 8);
#pragma unroll
            for (int i = 0; i < 2; ++i)
#pragma unroll
                for (int j = 0; j < 4; ++j)
                    acc[i][j] = __builtin_amdgcn_mfma_f32_16x16x32_bf16(
                        af[i], bf[j], acc[i][j], 0, 0, 0);
        }
    }

    // Epilogue. C/D layout: col = lane&15, row = (lane>>4)*4 + reg  [m89-verified]
    const int cbase = bn + wn * 64 + (lane & 15);
    const int rbase = bm + wm * 32 + ((lane >> 4) << 2);
#pragma unroll
    for (int j = 0; j < 4; ++j) {
        const int col = cbase + j * 16;
        const float bj = bias[col];
#pragma unroll
        for (int i = 0; i < 2; ++i) {
#pragma unroll
            for (int r = 0; r < 4; ++r) {
                const int row = rbase + i * 16 + r;
                if (row < M) {
                    float v = acc[i][j][r] + bj;
                    if (RELU) v = fmaxf(v, 0.f);
                    if (OUT_BF16)
                        ((unsigned short*)Cout)[(size_t)row * D_H + col] = f2b(v);
                    else
                        ((float*)Cout)[(size_t)row * D_H + col] = v;
                }
            }
        }
    }
}

// ---------------- fp32 -> bf16 convert ----------------
__global__ __launch_bounds__(256) void f2b_kernel(
    const float* __restrict__ src, unsigned short* __restrict__ dst, int n4)
{
    const int i = blockIdx.x * 256 + threadIdx.x;
    if (i < n4) {
        const float4 v = ((const float4*)src)[i];
        ((ushort4*)dst)[i] = make_ushort4(f2b(v.x), f2b(v.y), f2b(v.z), f2b(v.w));
    }
}

// ---------------- CSR build (per etype, once per launch) ----------------
__global__ __launch_bounds__(256) void zero_int_kernel(int* p, int n)
{
    int i = blockIdx.x * 256 + threadIdx.x;
    if (i < n) p[i] = 0;
}

__global__ __launch_bounds__(256) void count_deg_kernel(
    const int* __restrict__ dst, int* __restrict__ cnt, int E)
{
    int e = blockIdx.x * 256 + threadIdx.x;
    if (e < E) atomicAdd(&cnt[dst[e]], 1);
}

__global__ __launch_bounds__(1024) void scan_kernel(
    const int* __restrict__ cnt, int* __restrict__ off, int* __restrict__ cursor, int n)
{
    __shared__ int tmp[1024];
    __shared__ int carry;
    if (threadIdx.x == 0) carry = 0;
    __syncthreads();
    for (int base = 0; base < n; base += 1024) {
        const int i = base + threadIdx.x;
        const int v = (i < n) ? cnt[i] : 0;
        tmp[threadIdx.x] = v;
        __syncthreads();
#pragma unroll
        for (int o = 1; o < 1024; o <<= 1) {
            const int t = (threadIdx.x >= o) ? tmp[threadIdx.x - o] : 0;
            __syncthreads();
            tmp[threadIdx.x] += t;
            __syncthreads();
        }
        const int total = tmp[1023];
        if (i < n) {
            const int incl = tmp[threadIdx.x];
            off[i + 1] = carry + incl;
            cursor[i] = carry + incl - v;
        }
        __syncthreads();
        if (threadIdx.x == 0) carry += total;
        __syncthreads();
    }
    if (threadIdx.x == 0) off[0] = 0;
}

__global__ __launch_bounds__(256) void fill_csr_kernel(
    const int* __restrict__ src, const int* __restrict__ dst,
    int* __restrict__ cursor, int* __restrict__ esrc, int E)
{
    int e = blockIdx.x * 256 + threadIdx.x;
    if (e < E) {
        const int pos = atomicAdd(&cursor[dst[e]], 1);
        esrc[pos] = src[e];
    }
}

// ---------------- segment max (bf16): one wave per dst node ----------------
__device__ __forceinline__ ushort4 umax4(ushort4 a, ushort4 b)
{
    a.x = a.x > b.x ? a.x : b.x;
    a.y = a.y > b.y ? a.y : b.y;
    a.z = a.z > b.z ? a.z : b.z;
    a.w = a.w > b.w ? a.w : b.w;
    return a;
}

__global__ __launch_bounds__(256) void seg_max_kernel(
    const unsigned short* __restrict__ hp, const int* __restrict__ off,
    const int* __restrict__ esrc, unsigned short* __restrict__ neigh, int n)
{
    const int node = blockIdx.x * 4 + (threadIdx.x >> 6);
    if (node >= n) return;
    const int lane = threadIdx.x & 63;
    const int e0 = off[node], e1 = off[node + 1];
    ushort4 acc = make_ushort4(0, 0, 0, 0);
    int e = e0;
    for (; e + 4 <= e1; e += 4) {
        const int s0 = esrc[e + 0], s1 = esrc[e + 1];
        const int s2 = esrc[e + 2], s3 = esrc[e + 3];
        const ushort4 v0 = *(const ushort4*)(hp + (size_t)s0 * D_H + lane * 4);
        const ushort4 v1 = *(const ushort4*)(hp + (size_t)s1 * D_H + lane * 4);
        const ushort4 v2 = *(const ushort4*)(hp + (size_t)s2 * D_H + lane * 4);
        const ushort4 v3 = *(const ushort4*)(hp + (size_t)s3 * D_H + lane * 4);
        acc = umax4(umax4(umax4(acc, v0), umax4(v1, v2)), v3);
    }
    for (; e < e1; ++e) {
        const int s = esrc[e];
        acc = umax4(acc, *(const ushort4*)(hp + (size_t)s * D_H + lane * 4));
    }
    *(ushort4*)(neigh + (size_t)node * D_H + lane * 4) = acc;
}

// ---------------- LayerNorm (+relu, +accumulate), one wave per row ----------------
// MODE 0: write fp32 partial. MODE 1: add partial, write bf16. MODE 2: add partial, write fp32.
template <int MODE>
__global__ __launch_bounds__(256) void ln_kernel(
    const float* __restrict__ rst, const float* __restrict__ gamma,
    const float* __restrict__ beta, const float* __restrict__ add_src,
    void* __restrict__ outp, int n, int relu)
{
    const int row = blockIdx.x * 4 + (threadIdx.x >> 6);
    if (row >= n) return;
    const int lane = threadIdx.x & 63;
    float4 v = *(const float4*)(rst + (size_t)row * D_H + lane * 4);
    if (relu) {
        v.x = fmaxf(v.x, 0.f); v.y = fmaxf(v.y, 0.f);
        v.z = fmaxf(v.z, 0.f); v.w = fmaxf(v.w, 0.f);
    }
    float s = v.x + v.y + v.z + v.w;
#pragma unroll
    for (int o = 32; o > 0; o >>= 1) s += __shfl_xor(s, o);
    const float mean = s * (1.f / 256.f);
    const float d0 = v.x - mean, d1 = v.y - mean, d2 = v.z - mean, d3 = v.w - mean;
    float q = d0 * d0 + d1 * d1 + d2 * d2 + d3 * d3;
#pragma unroll
    for (int o = 32; o > 0; o >>= 1) q += __shfl_xor(q, o);
    const float inv = rsqrtf(q * (1.f / 256.f) + 1e-5f);
    const float4 g = *(const float4*)(gamma + lane * 4);
    const float4 b = *(const float4*)(beta + lane * 4);
    float4 o;
    o.x = d0 * inv * g.x + b.x;
    o.y = d1 * inv * g.y + b.y;
    o.z = d2 * inv * g.z + b.z;
    o.w = d3 * inv * g.w + b.w;
    if (MODE >= 1) {
        const float4 p = *(const float4*)(add_src + (size_t)row * D_H + lane * 4);
        o.x += p.x; o.y += p.y; o.z += p.z; o.w += p.w;
    }
    if (MODE == 1) {
        *(ushort4*)((unsigned short*)outp + (size_t)row * D_H + lane * 4) =
            make_ushort4(f2b(o.x), f2b(o.y), f2b(o.z), f2b(o.w));
    } else if (MODE == 0) {
        *(float4*)((float*)outp + (size_t)row * D_H + lane * 4) = o;
    } else {
        *(float4*)((float*)outp + (size_t)row * D_H + lane * 4) = o;
    }
}

extern "C" void kernel_launch(void* const* d_in, const int* in_sizes, int n_in,
                              void* d_out, int out_size, void* d_ws, size_t ws_size,
                              hipStream_t stream)
{
    const float* x      = (const float*)d_in[0];
    const int*   src    = (const int*)d_in[1];
    const int*   dst    = (const int*)d_in[2];
    const float* Wlin   = (const float*)d_in[3];
    const float* blin   = (const float*)d_in[4];
    const float* Wpool  = (const float*)d_in[5];
    const float* bpool  = (const float*)d_in[6];
    const float* Wself  = (const float*)d_in[7];
    const float* Wneigh = (const float*)d_in[8];
    const float* bconv  = (const float*)d_in[9];
    const float* gamma  = (const float*)d_in[10];
    const float* beta   = (const float*)d_in[11];

    const size_t NB = (size_t)N_NODES * D_H;             // 5.12M elems
    char* p = (char*)d_ws;
    // Region R1 (NB floats = 20.48 MB): x_bf16 (until lin GEMM), then per-t hp (bf16)
    // then rst (fp32). All sequentially dead — safe aliasing.
    float*          rstf = (float*)p;
    unsigned short* x_b  = (unsigned short*)p;
    unsigned short* hp_b = (unsigned short*)p;
    p += NB * 4;
    unsigned short* h_a     = (unsigned short*)p; p += NB * 2;
    unsigned short* h_b     = (unsigned short*)p; p += NB * 2;
    unsigned short* neigh_b = (unsigned short*)p; p += NB * 2;
    float*          partial = (float*)p;          p += NB * 4;
    unsigned short* wlin_b  = (unsigned short*)p; p += (size_t)D_H * F_IN * 2;
    unsigned short* wpool_b = (unsigned short*)p; p += (size_t)L_LAYERS * T_ETYPES * D_H * D_H * 2;
    unsigned short* wself_b = (unsigned short*)p; p += (size_t)L_LAYERS * T_ETYPES * D_H * D_H * 2;
    unsigned short* wneigh_b= (unsigned short*)p; p += (size_t)L_LAYERS * T_ETYPES * D_H * D_H * 2;
    int* ip = (int*)p;
    int* off[T_ETYPES];
    int* cur[T_ETYPES];
    int* esrc[T_ETYPES];
    for (int t = 0; t < T_ETYPES; ++t) { off[t] = ip; ip += (N_NODES + 1); }
    for (int t = 0; t < T_ETYPES; ++t) { cur[t] = ip; ip += N_NODES; }
    for (int t = 0; t < T_ETYPES; ++t) { esrc[t] = ip; ip += E_EDGES; }

    const dim3 blk(256);
    const dim3 ggrid(2, (N_NODES + 63) / 64);            // N/128 x M/64
    const dim3 egrid((E_EDGES + 255) / 256);
    const dim3 ngrid((N_NODES + 255) / 256);
    const dim3 wgrid((N_NODES + 3) / 4);

    // ---- bf16 conversions (weights once; x once) ----
    f2b_kernel<<<dim3((N_NODES * F_IN / 4 + 255) / 256), blk, 0, stream>>>(x, x_b, N_NODES * F_IN / 4);
    f2b_kernel<<<dim3((D_H * F_IN / 4 + 255) / 256), blk, 0, stream>>>(Wlin, wlin_b, D_H * F_IN / 4);
    const int WN4 = L_LAYERS * T_ETYPES * D_H * D_H / 4;
    f2b_kernel<<<dim3((WN4 + 255) / 256), blk, 0, stream>>>(Wpool, wpool_b, WN4);
    f2b_kernel<<<dim3((WN4 + 255) / 256), blk, 0, stream>>>(Wself, wself_b, WN4);
    f2b_kernel<<<dim3((WN4 + 255) / 256), blk, 0, stream>>>(Wneigh, wneigh_b, WN4);

    // ---- build CSR for both etypes (reused across all layers) ----
    for (int t = 0; t < T_ETYPES; ++t) {
        const int* dst_t = dst + (size_t)t * E_EDGES;
        const int* src_t = src + (size_t)t * E_EDGES;
        zero_int_kernel<<<ngrid, blk, 0, stream>>>(cur[t], N_NODES);
        count_deg_kernel<<<egrid, blk, 0, stream>>>(dst_t, cur[t], E_EDGES);
        scan_kernel<<<1, 1024, 0, stream>>>(cur[t], off[t], cur[t], N_NODES);
        fill_csr_kernel<<<egrid, blk, 0, stream>>>(src_t, dst_t, cur[t], esrc[t], E_EDGES);
    }

    // h0 = bf16( x @ Wlin^T + blin )
    gemm_mfma<1, 1, 0><<<ggrid, blk, 0, stream>>>(x_b, nullptr, wlin_b, nullptr,
                                                  blin, h_a, N_NODES, F_IN);

    unsigned short* h = h_a;
    unsigned short* hn = h_b;
    for (int l = 0; l < L_LAYERS; ++l) {
        const int relu = (l < L_LAYERS - 1) ? 1 : 0;
        for (int t = 0; t < T_ETYPES; ++t) {
            const size_t wo = ((size_t)l * T_ETYPES + t) * D_H * D_H;
            const size_t bo = ((size_t)l * T_ETYPES + t) * D_H;
            // hp = bf16(relu(h @ Wpool^T + bpool))
            gemm_mfma<1, 1, 1><<<ggrid, blk, 0, stream>>>(h, nullptr, wpool_b + wo, nullptr,
                                                          bpool + bo, hp_b, N_NODES, D_H);
            // neigh = segment_max (0 for zero-degree; hp >= 0 so u16 max == float max)
            seg_max_kernel<<<wgrid, blk, 0, stream>>>(hp_b, off[t], esrc[t], neigh_b, N_NODES);
            // rst = h @ Wself^T + neigh @ Wneigh^T + bconv   (fp32 out, overwrites hp region)
            gemm_mfma<2, 0, 0><<<ggrid, blk, 0, stream>>>(h, neigh_b, wself_b + wo, wneigh_b + wo,
                                                          bconv + bo, rstf, N_NODES, D_H);
            // out (+)= LN(maybe_relu(rst))
            if (t == 0) {
                ln_kernel<0><<<wgrid, blk, 0, stream>>>(rstf, gamma + bo, beta + bo, nullptr,
                                                        partial, N_NODES, relu);
            } else if (l < L_LAYERS - 1) {
                ln_kernel<1><<<wgrid, blk, 0, stream>>>(rstf, gamma + bo, beta + bo, partial,
                                                        hn, N_NODES, relu);
            } else {
                ln_kernel<2><<<wgrid, blk, 0, stream>>>(rstf, gamma + bo, beta + bo, partial,
                                                        d_out, N_NODES, relu);
            }
        }
        unsigned short* tmp = h; h = hn; hn = tmp;
    }
}